// Round 1
// baseline (1653.125 us; speedup 1.0000x reference)
//
#include <hip/hip_runtime.h>
#include <cstdint>

#define B_SZ 1024

// ---------------------------------------------------------------------------
// Threefry-2x32 (20 rounds), exactly as jax._src.prng.threefry2x32.
// ---------------------------------------------------------------------------
__host__ __device__ inline void tf2x32(uint32_t k0, uint32_t k1,
                                       uint32_t x0, uint32_t x1,
                                       uint32_t& o0, uint32_t& o1) {
  uint32_t ks2 = 0x1BD11BDAu ^ k0 ^ k1;
#define TF_RND(r) { x0 += x1; x1 = (x1 << (r)) | (x1 >> (32 - (r))); x1 ^= x0; }
  x0 += k0; x1 += k1;
  TF_RND(13) TF_RND(15) TF_RND(26) TF_RND(6)
  x0 += k1; x1 += ks2 + 1u;
  TF_RND(17) TF_RND(29) TF_RND(16) TF_RND(24)
  x0 += ks2; x1 += k0 + 2u;
  TF_RND(13) TF_RND(15) TF_RND(26) TF_RND(6)
  x0 += k0; x1 += k1 + 3u;
  TF_RND(17) TF_RND(29) TF_RND(16) TF_RND(24)
  x0 += k1; x1 += ks2 + 4u;
  TF_RND(13) TF_RND(15) TF_RND(26) TF_RND(6)
  x0 += ks2; x1 += k0 + 5u;
#undef TF_RND
  o0 = x0; o1 = x1;
}

// XLA ErfInv f32 expansion (Giles), identical coefficients.
__device__ inline float erfinv_f32(float x) {
  float w = -log1pf(-x * x);
  float p;
  if (w < 5.0f) {
    w -= 2.5f;
    p = 2.81022636e-08f;
    p = fmaf(p, w, 3.43273939e-07f);
    p = fmaf(p, w, -3.5233877e-06f);
    p = fmaf(p, w, -4.39150654e-06f);
    p = fmaf(p, w, 0.00021858087f);
    p = fmaf(p, w, -0.00125372503f);
    p = fmaf(p, w, -0.00417768164f);
    p = fmaf(p, w, 0.246640727f);
    p = fmaf(p, w, 1.50140941f);
  } else {
    w = sqrtf(w) - 3.0f;
    p = -0.000200214257f;
    p = fmaf(p, w, 0.000100950558f);
    p = fmaf(p, w, 0.00134934322f);
    p = fmaf(p, w, -0.00367342844f);
    p = fmaf(p, w, 0.00573950773f);
    p = fmaf(p, w, -0.0076224613f);
    p = fmaf(p, w, 0.00943887047f);
    p = fmaf(p, w, 1.00167406f);
    p = fmaf(p, w, 2.83297682f);
  }
  return p * x;
}

// jax.random.normal element e of a flat array, partitionable threefry mode
// (default since jax 0.4.36): bits = r0 ^ r1 of threefry(key, (hi64=0, e)).
__device__ inline float jax_normal_pt(uint32_t k0, uint32_t k1, uint32_t e) {
  uint32_t o0, o1;
  tf2x32(k0, k1, 0u, e, o0, o1);
  uint32_t bits = o0 ^ o1;
  float f = __uint_as_float((bits >> 9) | 0x3f800000u) - 1.0f;
  const float LO = -0.99999994f;            // nextafter(-1,0) in f32
  float u = fmaxf(LO, fmaf(f, 2.0f, LO));   // (hi-lo) rounds to 2.0f in f32
  return 1.41421356f * erfinv_f32(u);       // f32(sqrt(2)) = 0x3FB504F3
}

// ---------------------------------------------------------------------------
// One block per (b, stage I).  C = FEAT_C[I], S = SPATIAL[I], STRIDE.
// ---------------------------------------------------------------------------
template<int I, int C, int S, int STRIDE>
__global__ __launch_bounds__(256)
void ood_stage(const float* __restrict__ x,        // (B,3,32,32)
               const float* __restrict__ noise_w,  // (15,3,3,3)
               const float* __restrict__ noise_b,  // (15,)
               const float* __restrict__ feat_w,   // (C,3,3,3)
               const float* __restrict__ feat_b,   // (C,)
               const float* __restrict__ mu_w,     // (10,S)
               const float* __restrict__ mu_b,     // (10,)
               const float* __restrict__ std_w,    // (10,S)
               const float* __restrict__ std_b,    // (10,)
               float* __restrict__ mean_out,       // (B,C)
               float* __restrict__ std_out,        // (B,C)
               float* __restrict__ score_out,      // (B,5) in ws
               uint32_t fk0, uint32_t fk1) {
  constexpr int W  = 32 / STRIDE;              // output width (power of 2)
  constexpr int PL = (STRIDE == 1) ? 1 : 0;    // JAX SAME pad_lo
  constexpr int CH = (S < 256) ? S : 256;      // s-chunk staged in LDS

  const int b   = blockIdx.x;
  const int tid = threadIdx.x;

  __shared__ float s_x[3072];        // x[b]  (3,32,32)
  __shared__ float s_xi[3072];       // noised slice
  __shared__ float s_w[2][10 * CH];  // mu/std weight chunk
  __shared__ float s_g[2][10][27];   // fused patch-correlations
  __shared__ float s_rs[2][10];      // row sums of mu_w/std_w
  __shared__ float s_std[10 * C];    // x_std for all classes
  __shared__ float s_part[10][4];    // per-wave mahal partials
  __shared__ float s_nw[81];
  __shared__ float s_nb[3];
  __shared__ int   s_idx;

  // ---- load x[b], noise weights ----
  const float* xb = x + (size_t)b * 3072;
  for (int p = tid; p < 3072; p += 256) s_x[p] = xb[p];
  if (tid < 81) s_nw[tid] = noise_w[3 * I * 27 + tid];
  if (tid < 3)  s_nb[tid] = noise_b[3 * I + tid];
  __syncthreads();

  // ---- xi = x + conv3x3(x, noise_w[3I..3I+2]), SAME stride 1 ----
  for (int p = tid; p < 3072; p += 256) {
    int ci = p >> 10; int rr = p & 1023; int yy = rr >> 5; int xx = rr & 31;
    float acc = s_nb[ci];
    #pragma unroll
    for (int c2 = 0; c2 < 3; ++c2) {
      #pragma unroll
      for (int dy = 0; dy < 3; ++dy) {
        int y2 = yy + dy - 1;
        if (y2 < 0 || y2 > 31) continue;
        #pragma unroll
        for (int dx = 0; dx < 3; ++dx) {
          int x2 = xx + dx - 1;
          if (x2 < 0 || x2 > 31) continue;
          acc = fmaf(s_x[c2 * 1024 + y2 * 32 + x2],
                     s_nw[ci * 27 + c2 * 9 + dy * 3 + dx], acc);
        }
      }
    }
    s_xi[p] = acc + s_x[p];
  }

  // ---- g[which][k][ci,dy,dx] = sum_s w[k,s]*xi[ci, patch(s)] ; row sums ----
  // 540 correlation slots + 20 row-sum slots over 256 threads (3 each).
  int a_k[3], a_ci[3], a_dy[3], a_dx[3], a_wh[3];
  bool a_valid[3], a_rsum[3];
  #pragma unroll
  for (int a = 0; a < 3; ++a) {
    int m = tid + a * 256;
    a_valid[a] = (m < 560);
    a_rsum[a]  = (m >= 540 && m < 560);
    if (m < 540) {
      a_wh[a] = m / 270; int rem = m % 270;
      a_k[a] = rem / 27; int j = rem % 27;
      a_ci[a] = j / 9; a_dy[a] = (j % 9) / 3; a_dx[a] = j % 3;
    } else if (m < 560) {
      int r = m - 540; a_wh[a] = r / 10; a_k[a] = r % 10;
      a_ci[a] = a_dy[a] = a_dx[a] = 0;
    } else {
      a_wh[a] = a_k[a] = a_ci[a] = a_dy[a] = a_dx[a] = 0;
    }
  }

  float acc[3] = {0.f, 0.f, 0.f};
  for (int s0 = 0; s0 < S; s0 += CH) {
    __syncthreads();
    for (int v = tid; v < 2 * 10 * CH; v += 256) {
      int which = v / (10 * CH); int rem = v - which * 10 * CH;
      int kk = rem / CH; int cc = rem - kk * CH;
      const float* src = which ? std_w : mu_w;
      s_w[which][kk * CH + cc] = src[kk * S + s0 + cc];
    }
    __syncthreads();
    for (int cc = 0; cc < CH; ++cc) {
      int s = s0 + cc;
      int yo = s / W; int xo = s - yo * W;
      #pragma unroll
      for (int a = 0; a < 3; ++a) {
        if (!a_valid[a]) continue;
        float wv = s_w[a_wh[a]][a_k[a] * CH + cc];
        float v;
        if (a_rsum[a]) {
          v = 1.0f;
        } else {
          int yy = yo * STRIDE + a_dy[a] - PL;
          int xx = xo * STRIDE + a_dx[a] - PL;
          v = (yy >= 0 && yy < 32 && xx >= 0 && xx < 32)
                  ? s_xi[a_ci[a] * 1024 + yy * 32 + xx] : 0.0f;
        }
        acc[a] = fmaf(wv, v, acc[a]);
      }
    }
  }
  #pragma unroll
  for (int a = 0; a < 3; ++a) {
    int m = tid + a * 256;
    if (m < 540) {
      int rem = m % 270;
      s_g[a_wh[a]][rem / 27][rem % 27] = acc[a];
    } else if (m < 560) {
      s_rs[a_wh[a]][a_k[a]] = acc[a];
    }
  }
  __syncthreads();

  // ---- x_std[k,c] for all classes (mean recomputed later for argmax class)
  for (int v = tid; v < 10 * C; v += 256) {
    int k = v / C; int c = v - k * C;
    const float* fw = feat_w + c * 27;
    float a2 = 0.f;
    #pragma unroll
    for (int j = 0; j < 27; ++j) a2 = fmaf(s_g[1][k][j], fw[j], a2);
    a2 = fmaf(feat_b[c], s_rs[1][k], a2) + std_b[k];
    s_std[v] = a2;
  }
  __syncthreads();

  // ---- mahal[k] = -0.5 * sum_c var*eps^2 with jax-exact eps ----
  float macc[10];
  #pragma unroll
  for (int k = 0; k < 10; ++k) macc[k] = 0.f;
  for (int c = tid; c < C; c += 256) {
    #pragma unroll
    for (int k = 0; k < 10; ++k) {
      float sd  = s_std[k * C + c];
      float var = sd * sd;
      uint32_t e = (uint32_t)((b * 10 + k) * C + c);
      float eps = jax_normal_pt(fk0, fk1, e);
      macc[k] = fmaf(var, eps * eps, macc[k]);
    }
  }
  int lane = tid & 63, wv = tid >> 6;
  #pragma unroll
  for (int k = 0; k < 10; ++k) {
    float v = macc[k];
    #pragma unroll
    for (int off = 32; off > 0; off >>= 1) v += __shfl_down(v, off, 64);
    if (lane == 0) s_part[k][wv] = v;
  }
  __syncthreads();
  if (tid == 0) {
    float best = -INFINITY; int bi = 0;
    #pragma unroll
    for (int k = 0; k < 10; ++k) {
      float m = -0.5f * (s_part[k][0] + s_part[k][1] + s_part[k][2] + s_part[k][3]);
      if (m > best) { best = m; bi = k; }
    }
    score_out[b * 5 + I] = best;
    s_idx = bi;
  }
  __syncthreads();

  // ---- outputs: mean (recomputed for idx) and std for selected class ----
  int idx = s_idx;
  for (int c = tid; c < C; c += 256) {
    const float* fw = feat_w + c * 27;
    float a1 = 0.f;
    #pragma unroll
    for (int j = 0; j < 27; ++j) a1 = fmaf(s_g[0][idx][j], fw[j], a1);
    a1 = fmaf(feat_b[c], s_rs[0][idx], a1) + mu_b[idx];
    mean_out[(size_t)b * C + c] = a1;
    std_out[(size_t)b * C + c]  = s_std[idx * C + c];
  }
}

__global__ void ood_clf(const float* __restrict__ scores,  // (B,5)
                        const float* __restrict__ clf_w,   // (1,5)
                        const float* __restrict__ clf_b,   // (1,)
                        float* __restrict__ out) {         // (B,)
  int b = blockIdx.x * blockDim.x + threadIdx.x;
  if (b < B_SZ) {
    float acc = clf_b[0];
    #pragma unroll
    for (int i = 0; i < 5; ++i) acc = fmaf(scores[b * 5 + i], clf_w[i], acc);
    out[b] = acc;
  }
}

extern "C" void kernel_launch(void* const* d_in, const int* in_sizes, int n_in,
                              void* d_out, int out_size, void* d_ws, size_t ws_size,
                              hipStream_t stream) {
  (void)in_sizes; (void)n_in; (void)out_size; (void)ws_size;
  const float* x       = (const float*)d_in[0];
  const float* noise_w = (const float*)d_in[1];
  const float* noise_b = (const float*)d_in[2];
  const float* clf_w   = (const float*)d_in[33];
  const float* clf_b   = (const float*)d_in[34];
  float* out    = (float*)d_out;
  float* scores = (float*)d_ws;   // B*5 floats

  // fold_in(key(42), i) = threefry((0,42),(0,i))
  uint32_t fk0[5], fk1[5];
  for (uint32_t i = 0; i < 5; ++i) tf2x32(0u, 42u, 0u, i, fk0[i], fk1[i]);

  // output layout: out(1024) | means0..4 (B*C each) | stds0..4
  const size_t NMEAN = 1048576;
  const size_t moff[5] = {1024, 66560, 132096, 263168, 525312};

#define LAUNCH(i, C, S, STR)                                                   \
  ood_stage<i, C, S, STR><<<B_SZ, 256, 0, stream>>>(                           \
      x, noise_w, noise_b,                                                     \
      (const float*)d_in[3 + 6 * i], (const float*)d_in[4 + 6 * i],            \
      (const float*)d_in[5 + 6 * i], (const float*)d_in[6 + 6 * i],            \
      (const float*)d_in[7 + 6 * i], (const float*)d_in[8 + 6 * i],            \
      out + moff[i], out + moff[i] + NMEAN, scores, fk0[i], fk1[i]);

  LAUNCH(0, 64, 1024, 1)
  LAUNCH(1, 64, 1024, 1)
  LAUNCH(2, 128, 256, 2)
  LAUNCH(3, 256, 64, 4)
  LAUNCH(4, 512, 16, 8)
#undef LAUNCH

  ood_clf<<<(B_SZ + 255) / 256, 256, 0, stream>>>(scores, clf_w, clf_b, out);
}

// Round 2
// 902.309 us; speedup vs baseline: 1.8321x; 1.8321x over previous
//
#include <hip/hip_runtime.h>
#include <cstdint>

#define B_SZ 1024

// ---------------------------------------------------------------------------
// Threefry-2x32 (20 rounds), exactly as jax._src.prng.threefry2x32.
// ---------------------------------------------------------------------------
__host__ __device__ inline void tf2x32(uint32_t k0, uint32_t k1,
                                       uint32_t x0, uint32_t x1,
                                       uint32_t& o0, uint32_t& o1) {
  uint32_t ks2 = 0x1BD11BDAu ^ k0 ^ k1;
#define TF_RND(r) { x0 += x1; x1 = (x1 << (r)) | (x1 >> (32 - (r))); x1 ^= x0; }
  x0 += k0; x1 += k1;
  TF_RND(13) TF_RND(15) TF_RND(26) TF_RND(6)
  x0 += k1; x1 += ks2 + 1u;
  TF_RND(17) TF_RND(29) TF_RND(16) TF_RND(24)
  x0 += ks2; x1 += k0 + 2u;
  TF_RND(13) TF_RND(15) TF_RND(26) TF_RND(6)
  x0 += k0; x1 += k1 + 3u;
  TF_RND(17) TF_RND(29) TF_RND(16) TF_RND(24)
  x0 += k1; x1 += ks2 + 4u;
  TF_RND(13) TF_RND(15) TF_RND(26) TF_RND(6)
  x0 += ks2; x1 += k0 + 5u;
#undef TF_RND
  o0 = x0; o1 = x1;
}

// XLA ErfInv f32 expansion, identical coefficients.
__device__ inline float erfinv_f32(float x) {
  float w = -log1pf(-x * x);
  float p;
  if (w < 5.0f) {
    w -= 2.5f;
    p = 2.81022636e-08f;
    p = fmaf(p, w, 3.43273939e-07f);
    p = fmaf(p, w, -3.5233877e-06f);
    p = fmaf(p, w, -4.39150654e-06f);
    p = fmaf(p, w, 0.00021858087f);
    p = fmaf(p, w, -0.00125372503f);
    p = fmaf(p, w, -0.00417768164f);
    p = fmaf(p, w, 0.246640727f);
    p = fmaf(p, w, 1.50140941f);
  } else {
    w = sqrtf(w) - 3.0f;
    p = -0.000200214257f;
    p = fmaf(p, w, 0.000100950558f);
    p = fmaf(p, w, 0.00134934322f);
    p = fmaf(p, w, -0.00367342844f);
    p = fmaf(p, w, 0.00573950773f);
    p = fmaf(p, w, -0.0076224613f);
    p = fmaf(p, w, 0.00943887047f);
    p = fmaf(p, w, 1.00167406f);
    p = fmaf(p, w, 2.83297682f);
  }
  return p * x;
}

__device__ inline float jax_normal_pt(uint32_t k0, uint32_t k1, uint32_t e) {
  uint32_t o0, o1;
  tf2x32(k0, k1, 0u, e, o0, o1);
  uint32_t bits = o0 ^ o1;
  float f = __uint_as_float((bits >> 9) | 0x3f800000u) - 1.0f;
  const float LO = -0.99999994f;
  float u = fmaxf(LO, fmaf(f, 2.0f, LO));
  return 1.41421356f * erfinv_f32(u);
}

// ---------------------------------------------------------------------------
// One block per (b, stage I). 320 threads: 20 (wh,k) groups x 16 spatial subs.
// ---------------------------------------------------------------------------
template<int I, int C, int S, int STRIDE>
__global__ __launch_bounds__(320, 5)
void ood_stage(const float* __restrict__ x,        // (B,3,32,32)
               const float* __restrict__ noise_w,  // (15,3,3,3)
               const float* __restrict__ noise_b,  // (15,)
               const float* __restrict__ feat_w,   // (C,3,3,3)
               const float* __restrict__ feat_b,   // (C,)
               const float* __restrict__ mu_w,     // (10,S)
               const float* __restrict__ mu_b,     // (10,)
               const float* __restrict__ std_w,    // (10,S)
               const float* __restrict__ std_b,    // (10,)
               float* __restrict__ mean_out,       // (B,C)
               float* __restrict__ std_out,        // (B,C)
               float* __restrict__ score_out,      // (B,5) in ws
               uint32_t fk0, uint32_t fk1) {
  constexpr int Wd = 32 / STRIDE;   // output width

  const int b = blockIdx.x;
  const int t = threadIdx.x;

  __shared__ float s_x[3072];        // x[b] (3,32,32)
  __shared__ float s_xi[3 * 34 * 34]; // zero-padded noised slice [3][34][34]
  __shared__ float s_g[2][10][27];
  __shared__ float s_rs[2][10];
  __shared__ float s_part[10][5];
  __shared__ float s_nw[81];
  __shared__ float s_nb[3];
  __shared__ int   s_idx;

  // ---- phase 1: load x[b], zero padded xi, noise weights ----
  const float* xb = x + (size_t)b * 3072;
  for (int p = t; p < 3072; p += 320) s_x[p] = xb[p];
  for (int p = t; p < 3 * 34 * 34; p += 320) s_xi[p] = 0.0f;
  if (t < 81) s_nw[t] = noise_w[81 * I + t];
  if (t < 3)  s_nb[t] = noise_b[3 * I + t];
  __syncthreads();

  // ---- phase 2: xi = x + conv3x3(x, noise_w), into padded layout ----
  for (int p = t; p < 3072; p += 320) {
    int ci = p >> 10; int rr = p & 1023; int yy = rr >> 5; int xx = rr & 31;
    float acc = s_nb[ci];
    #pragma unroll
    for (int c2 = 0; c2 < 3; ++c2) {
      #pragma unroll
      for (int dy = 0; dy < 3; ++dy) {
        int y2 = yy + dy - 1;
        if (y2 < 0 || y2 > 31) continue;
        #pragma unroll
        for (int dx = 0; dx < 3; ++dx) {
          int x2 = xx + dx - 1;
          if (x2 < 0 || x2 > 31) continue;
          acc = fmaf(s_x[c2 * 1024 + y2 * 32 + x2],
                     s_nw[ci * 27 + c2 * 9 + dy * 3 + dx], acc);
        }
      }
    }
    s_xi[ci * 1156 + (yy + 1) * 34 + (xx + 1)] = acc + s_x[p];
  }
  __syncthreads();

  // ---- phase 3: g[wh][k][j] = sum_s w[k,s]*xi[patch(s,j)], rowsum ----
  const int G  = t >> 4;          // 0..19
  const int ss = t & 15;          // spatial sub
  const int wh = G & 1;
  const int kk = G >> 1;
  const float* wsrc = (wh ? std_w : mu_w) + kk * S;

  float acc[28];
  #pragma unroll
  for (int j = 0; j < 28; ++j) acc[j] = 0.0f;

  if constexpr (STRIDE == 1) {
    // per thread: 2 rows of 32; sliding 3-column window, period-3 reg rotation
    for (int r = 0; r < 2; ++r) {
      const int row = 2 * ss + r;
      const int rb  = row * 34;          // padded y index == row+dy
      const float* wr = wsrc + row * 32;
      float A[9], Bv[9], Cv[9];
      #pragma unroll
      for (int q = 0; q < 9; ++q) {
        A[q]  = s_xi[(q / 3) * 1156 + rb + (q % 3) * 34 + 0];
        Bv[q] = s_xi[(q / 3) * 1156 + rb + (q % 3) * 34 + 1];
      }
      float4 w4a = *(const float4*)(wr + 0);
      float4 w4b = *(const float4*)(wr + 4);
      float4 w4c = *(const float4*)(wr + 8);
      float4 w4d = *(const float4*)(wr + 12);

#define WCOMP(V, L) ((L) == 0 ? (V).x : (L) == 1 ? (V).y : (L) == 2 ? (V).z : (V).w)
#define WVAL(XO) ((((XO) & 15) >> 2) == 0 ? WCOMP(w4a, (XO) & 3) : \
                  (((XO) & 15) >> 2) == 1 ? WCOMP(w4b, (XO) & 3) : \
                  (((XO) & 15) >> 2) == 2 ? WCOMP(w4c, (XO) & 3) : WCOMP(w4d, (XO) & 3))
#define STEP1(XO, P, Q, R) { \
    _Pragma("unroll") \
    for (int q = 0; q < 9; ++q) \
      R[q] = s_xi[(q / 3) * 1156 + rb + (q % 3) * 34 + ((XO) + 2)]; \
    const float wx = WVAL(XO); \
    _Pragma("unroll") \
    for (int q = 0; q < 9; ++q) { \
      acc[(q / 3) * 9 + (q % 3) * 3 + 0] = fmaf(wx, P[q], acc[(q / 3) * 9 + (q % 3) * 3 + 0]); \
      acc[(q / 3) * 9 + (q % 3) * 3 + 1] = fmaf(wx, Q[q], acc[(q / 3) * 9 + (q % 3) * 3 + 1]); \
      acc[(q / 3) * 9 + (q % 3) * 3 + 2] = fmaf(wx, R[q], acc[(q / 3) * 9 + (q % 3) * 3 + 2]); \
    } \
    acc[27] += wx; \
  }
#define S3(X) STEP1(X, A, Bv, Cv) STEP1((X) + 1, Bv, Cv, A) STEP1((X) + 2, Cv, A, Bv)

      S3(0) S3(3) S3(6) S3(9) S3(12) STEP1(15, A, Bv, Cv)
      w4a = *(const float4*)(wr + 16);
      w4b = *(const float4*)(wr + 20);
      w4c = *(const float4*)(wr + 24);
      w4d = *(const float4*)(wr + 28);
      STEP1(16, Bv, Cv, A) STEP1(17, Cv, A, Bv)
      S3(18) S3(21) S3(24) S3(27) STEP1(30, A, Bv, Cv) STEP1(31, Bv, Cv, A)

#undef S3
#undef STEP1
#undef WVAL
#undef WCOMP
    }
  } else {
    constexpr int PER = S / 16;          // 16 / 4 / 1
    #pragma unroll
    for (int u = 0; u < PER; ++u) {
      const int s  = ss * PER + u;
      const int yo = s / Wd, xo = s % Wd;
      const float wx = wsrc[s];
      #pragma unroll
      for (int q = 0; q < 9; ++q) {
        const int ci = q / 3, dy = q % 3;
        const int base = ci * 1156 + (yo * STRIDE + dy + 1) * 34 + (xo * STRIDE + 1);
        #pragma unroll
        for (int dx = 0; dx < 3; ++dx)
          acc[ci * 9 + dy * 3 + dx] = fmaf(wx, s_xi[base + dx], acc[ci * 9 + dy * 3 + dx]);
      }
      acc[27] += wx;
    }
  }

  // reduce across the 16 spatial subs (contiguous 16-lane groups)
  #pragma unroll
  for (int j = 0; j < 28; ++j) {
    float v = acc[j];
    v += __shfl_xor(v, 1, 64);
    v += __shfl_xor(v, 2, 64);
    v += __shfl_xor(v, 4, 64);
    v += __shfl_xor(v, 8, 64);
    acc[j] = v;
  }
  if (ss == 0) {
    #pragma unroll
    for (int j = 0; j < 27; ++j) s_g[wh][kk][j] = acc[j];
    s_rs[wh][kk] = acc[27];
  }
  __syncthreads();

  // ---- phase 4: fused std + eps + mahal (no s_std buffer) ----
  float macc[10];
  #pragma unroll
  for (int k2 = 0; k2 < 10; ++k2) macc[k2] = 0.0f;
  for (int c = t; c < C; c += 320) {
    float fw[27];
    #pragma unroll
    for (int j = 0; j < 27; ++j) fw[j] = feat_w[c * 27 + j];
    const float fb = feat_b[c];
    #pragma unroll
    for (int k2 = 0; k2 < 10; ++k2) {
      float a2 = 0.0f;
      #pragma unroll
      for (int j = 0; j < 27; ++j) a2 = fmaf(s_g[1][k2][j], fw[j], a2);
      a2 = fmaf(fb, s_rs[1][k2], a2) + std_b[k2];
      const float eps = jax_normal_pt(fk0, fk1, (uint32_t)((b * 10 + k2) * C + c));
      macc[k2] = fmaf(a2 * a2, eps * eps, macc[k2]);
    }
  }
  const int lane = t & 63, wvi = t >> 6;
  #pragma unroll
  for (int k2 = 0; k2 < 10; ++k2) {
    float v = macc[k2];
    #pragma unroll
    for (int off = 32; off > 0; off >>= 1) v += __shfl_down(v, off, 64);
    if (lane == 0) s_part[k2][wvi] = v;
  }
  __syncthreads();
  if (t == 0) {
    float best = -INFINITY; int bi = 0;
    #pragma unroll
    for (int k2 = 0; k2 < 10; ++k2) {
      float m = -0.5f * (s_part[k2][0] + s_part[k2][1] + s_part[k2][2] +
                         s_part[k2][3] + s_part[k2][4]);
      if (m > best) { best = m; bi = k2; }
    }
    score_out[b * 5 + I] = best;
    s_idx = bi;
  }
  __syncthreads();

  // ---- phase 5: outputs (mean & std recomputed for the argmax class) ----
  const int idx = s_idx;
  for (int c = t; c < C; c += 320) {
    float fw[27];
    #pragma unroll
    for (int j = 0; j < 27; ++j) fw[j] = feat_w[c * 27 + j];
    const float fb = feat_b[c];
    float a1 = 0.0f, a2 = 0.0f;
    #pragma unroll
    for (int j = 0; j < 27; ++j) {
      a1 = fmaf(s_g[0][idx][j], fw[j], a1);
      a2 = fmaf(s_g[1][idx][j], fw[j], a2);
    }
    a1 = fmaf(fb, s_rs[0][idx], a1) + mu_b[idx];
    a2 = fmaf(fb, s_rs[1][idx], a2) + std_b[idx];
    mean_out[(size_t)b * C + c] = a1;
    std_out[(size_t)b * C + c]  = a2;
  }
}

__global__ void ood_clf(const float* __restrict__ scores,  // (B,5)
                        const float* __restrict__ clf_w,   // (1,5)
                        const float* __restrict__ clf_b,   // (1,)
                        float* __restrict__ out) {         // (B,)
  int b = blockIdx.x * blockDim.x + threadIdx.x;
  if (b < B_SZ) {
    float acc = clf_b[0];
    #pragma unroll
    for (int i = 0; i < 5; ++i) acc = fmaf(scores[b * 5 + i], clf_w[i], acc);
    out[b] = acc;
  }
}

extern "C" void kernel_launch(void* const* d_in, const int* in_sizes, int n_in,
                              void* d_out, int out_size, void* d_ws, size_t ws_size,
                              hipStream_t stream) {
  (void)in_sizes; (void)n_in; (void)out_size; (void)ws_size;
  const float* x       = (const float*)d_in[0];
  const float* noise_w = (const float*)d_in[1];
  const float* noise_b = (const float*)d_in[2];
  const float* clf_w   = (const float*)d_in[33];
  const float* clf_b   = (const float*)d_in[34];
  float* out    = (float*)d_out;
  float* scores = (float*)d_ws;   // B*5 floats

  uint32_t fk0[5], fk1[5];
  for (uint32_t i = 0; i < 5; ++i) tf2x32(0u, 42u, 0u, i, fk0[i], fk1[i]);

  const size_t NMEAN = 1048576;
  const size_t moff[5] = {1024, 66560, 132096, 263168, 525312};

#define LAUNCH(i, C, S, STR)                                                   \
  ood_stage<i, C, S, STR><<<B_SZ, 320, 0, stream>>>(                           \
      x, noise_w, noise_b,                                                     \
      (const float*)d_in[3 + 6 * i], (const float*)d_in[4 + 6 * i],            \
      (const float*)d_in[5 + 6 * i], (const float*)d_in[6 + 6 * i],            \
      (const float*)d_in[7 + 6 * i], (const float*)d_in[8 + 6 * i],            \
      out + moff[i], out + moff[i] + NMEAN, scores, fk0[i], fk1[i]);

  LAUNCH(0, 64, 1024, 1)
  LAUNCH(1, 64, 1024, 1)
  LAUNCH(2, 128, 256, 2)
  LAUNCH(3, 256, 64, 4)
  LAUNCH(4, 512, 16, 8)
#undef LAUNCH

  ood_clf<<<(B_SZ + 255) / 256, 256, 0, stream>>>(scores, clf_w, clf_b, out);
}

// Round 3
// 827.862 us; speedup vs baseline: 1.9969x; 1.0899x over previous
//
#include <hip/hip_runtime.h>
#include <cstdint>

#define B_SZ 1024

// ---------------------------------------------------------------------------
// Threefry-2x32 (20 rounds), exactly as jax._src.prng.threefry2x32.
// ---------------------------------------------------------------------------
__host__ __device__ inline void tf2x32(uint32_t k0, uint32_t k1,
                                       uint32_t x0, uint32_t x1,
                                       uint32_t& o0, uint32_t& o1) {
  uint32_t ks2 = 0x1BD11BDAu ^ k0 ^ k1;
#define TF_RND(r) { x0 += x1; x1 = (x1 << (r)) | (x1 >> (32 - (r))); x1 ^= x0; }
  x0 += k0; x1 += k1;
  TF_RND(13) TF_RND(15) TF_RND(26) TF_RND(6)
  x0 += k1; x1 += ks2 + 1u;
  TF_RND(17) TF_RND(29) TF_RND(16) TF_RND(24)
  x0 += ks2; x1 += k0 + 2u;
  TF_RND(13) TF_RND(15) TF_RND(26) TF_RND(6)
  x0 += k0; x1 += k1 + 3u;
  TF_RND(17) TF_RND(29) TF_RND(16) TF_RND(24)
  x0 += k1; x1 += ks2 + 4u;
  TF_RND(13) TF_RND(15) TF_RND(26) TF_RND(6)
  x0 += ks2; x1 += k0 + 5u;
#undef TF_RND
  o0 = x0; o1 = x1;
}

// XLA ErfInv f32 expansion, identical coefficients.
__device__ inline float erfinv_f32(float x) {
  float w = -log1pf(-x * x);
  float p;
  if (w < 5.0f) {
    w -= 2.5f;
    p = 2.81022636e-08f;
    p = fmaf(p, w, 3.43273939e-07f);
    p = fmaf(p, w, -3.5233877e-06f);
    p = fmaf(p, w, -4.39150654e-06f);
    p = fmaf(p, w, 0.00021858087f);
    p = fmaf(p, w, -0.00125372503f);
    p = fmaf(p, w, -0.00417768164f);
    p = fmaf(p, w, 0.246640727f);
    p = fmaf(p, w, 1.50140941f);
  } else {
    w = sqrtf(w) - 3.0f;
    p = -0.000200214257f;
    p = fmaf(p, w, 0.000100950558f);
    p = fmaf(p, w, 0.00134934322f);
    p = fmaf(p, w, -0.00367342844f);
    p = fmaf(p, w, 0.00573950773f);
    p = fmaf(p, w, -0.0076224613f);
    p = fmaf(p, w, 0.00943887047f);
    p = fmaf(p, w, 1.00167406f);
    p = fmaf(p, w, 2.83297682f);
  }
  return p * x;
}

__device__ inline float jax_normal_pt(uint32_t k0, uint32_t k1, uint32_t e) {
  uint32_t o0, o1;
  tf2x32(k0, k1, 0u, e, o0, o1);
  uint32_t bits = o0 ^ o1;
  float f = __uint_as_float((bits >> 9) | 0x3f800000u) - 1.0f;
  const float LO = -0.99999994f;
  float u = fmaxf(LO, fmaf(f, 2.0f, LO));
  return 1.41421356f * erfinv_f32(u);
}

struct OodArgs {
  const float* x;
  const float* noise_w;
  const float* noise_b;
  const float* feat_w[5];
  const float* feat_b[5];
  const float* mu_w[5];
  const float* mu_b[5];
  const float* std_w[5];
  const float* std_b[5];
  float* mean_out[5];
  float* std_out[5];
  float* scores;
  uint32_t fk0[5], fk1[5];
};

// LDS carve offsets (floats)
#define OFF_X    0      // 3072
#define OFF_XI   3072   // 3*34*34 = 3468
#define OFF_G    6540   // 2*10*27 = 540
#define OFF_RS   7080   // 20
#define OFF_PART 7100   // 50
#define OFF_NW   7150   // 81
#define OFF_NB   7231   // 3
#define OFF_IDX  7235   // 1 (int)
#define SMEM_FLOATS 7236

// ---------------------------------------------------------------------------
// One block per (b, stage I). 320 threads: 20 (wh,k) groups x 16 spatial subs.
// ---------------------------------------------------------------------------
template<int I, int C, int S, int STRIDE>
__device__ __forceinline__ void stage_body(const OodArgs& A, float* smem) {
  constexpr int Wd = 32 / STRIDE;   // output width

  const int b = blockIdx.y;
  const int t = threadIdx.x;

  float* s_x  = smem + OFF_X;
  float* s_xi = smem + OFF_XI;
  float* s_g  = smem + OFF_G;      // [2][10][27]
  float* s_rs = smem + OFF_RS;     // [2][10]
  float* s_pt = smem + OFF_PART;   // [10][5]
  float* s_nw = smem + OFF_NW;
  float* s_nb = smem + OFF_NB;
  int*   s_idx = (int*)(smem + OFF_IDX);

  const float* feat_w = A.feat_w[I];
  const float* feat_b = A.feat_b[I];
  const uint32_t fk0 = A.fk0[I], fk1 = A.fk1[I];

  // ---- phase 1: load x[b], zero padded xi, noise weights ----
  const float* xb = A.x + (size_t)b * 3072;
  for (int p = t; p < 3072; p += 320) s_x[p] = xb[p];
  for (int p = t; p < 3 * 34 * 34; p += 320) s_xi[p] = 0.0f;
  if (t < 81) s_nw[t] = A.noise_w[81 * I + t];
  if (t < 3)  s_nb[t] = A.noise_b[3 * I + t];
  __syncthreads();

  // ---- phase 2: xi = x + conv3x3(x, noise_w), into padded layout ----
  for (int p = t; p < 3072; p += 320) {
    int ci = p >> 10; int rr = p & 1023; int yy = rr >> 5; int xx = rr & 31;
    float acc = s_nb[ci];
    #pragma unroll
    for (int c2 = 0; c2 < 3; ++c2) {
      #pragma unroll
      for (int dy = 0; dy < 3; ++dy) {
        int y2 = yy + dy - 1;
        if (y2 < 0 || y2 > 31) continue;
        #pragma unroll
        for (int dx = 0; dx < 3; ++dx) {
          int x2 = xx + dx - 1;
          if (x2 < 0 || x2 > 31) continue;
          acc = fmaf(s_x[c2 * 1024 + y2 * 32 + x2],
                     s_nw[ci * 27 + c2 * 9 + dy * 3 + dx], acc);
        }
      }
    }
    s_xi[ci * 1156 + (yy + 1) * 34 + (xx + 1)] = acc + s_x[p];
  }
  __syncthreads();

  // ---- phase 3: g[wh][k][j] = sum_s w[k,s]*xi[patch(s,j)], rowsum ----
  const int G  = t >> 4;          // 0..19
  const int ss = t & 15;          // spatial sub
  const int wh = G & 1;
  const int kk = G >> 1;
  const float* wsrc = (wh ? A.std_w[I] : A.mu_w[I]) + kk * S;

  float acc[28];
  #pragma unroll
  for (int j = 0; j < 28; ++j) acc[j] = 0.0f;

  if constexpr (STRIDE == 1) {
    // per thread: 2 rows of 32; sliding 3-column window, period-3 reg rotation
    for (int r = 0; r < 2; ++r) {
      const int row = 2 * ss + r;
      const int rb  = row * 34;          // padded y index == row+dy
      const float* wr = wsrc + row * 32;
      float Av[9], Bv[9], Cv[9];
      #pragma unroll
      for (int q = 0; q < 9; ++q) {
        Av[q] = s_xi[(q / 3) * 1156 + rb + (q % 3) * 34 + 0];
        Bv[q] = s_xi[(q / 3) * 1156 + rb + (q % 3) * 34 + 1];
      }
      float4 w4a = *(const float4*)(wr + 0);
      float4 w4b = *(const float4*)(wr + 4);
      float4 w4c = *(const float4*)(wr + 8);
      float4 w4d = *(const float4*)(wr + 12);

#define WCOMP(V, L) ((L) == 0 ? (V).x : (L) == 1 ? (V).y : (L) == 2 ? (V).z : (V).w)
#define WVAL(XO) ((((XO) & 15) >> 2) == 0 ? WCOMP(w4a, (XO) & 3) : \
                  (((XO) & 15) >> 2) == 1 ? WCOMP(w4b, (XO) & 3) : \
                  (((XO) & 15) >> 2) == 2 ? WCOMP(w4c, (XO) & 3) : WCOMP(w4d, (XO) & 3))
#define STEP1(XO, P, Q, R) { \
    _Pragma("unroll") \
    for (int q = 0; q < 9; ++q) \
      R[q] = s_xi[(q / 3) * 1156 + rb + (q % 3) * 34 + ((XO) + 2)]; \
    const float wx = WVAL(XO); \
    _Pragma("unroll") \
    for (int q = 0; q < 9; ++q) { \
      acc[(q / 3) * 9 + (q % 3) * 3 + 0] = fmaf(wx, P[q], acc[(q / 3) * 9 + (q % 3) * 3 + 0]); \
      acc[(q / 3) * 9 + (q % 3) * 3 + 1] = fmaf(wx, Q[q], acc[(q / 3) * 9 + (q % 3) * 3 + 1]); \
      acc[(q / 3) * 9 + (q % 3) * 3 + 2] = fmaf(wx, R[q], acc[(q / 3) * 9 + (q % 3) * 3 + 2]); \
    } \
    acc[27] += wx; \
  }
#define S3(X) STEP1(X, Av, Bv, Cv) STEP1((X) + 1, Bv, Cv, Av) STEP1((X) + 2, Cv, Av, Bv)

      S3(0) S3(3) S3(6) S3(9) S3(12) STEP1(15, Av, Bv, Cv)
      w4a = *(const float4*)(wr + 16);
      w4b = *(const float4*)(wr + 20);
      w4c = *(const float4*)(wr + 24);
      w4d = *(const float4*)(wr + 28);
      STEP1(16, Bv, Cv, Av) STEP1(17, Cv, Av, Bv)
      S3(18) S3(21) S3(24) S3(27) STEP1(30, Av, Bv, Cv) STEP1(31, Bv, Cv, Av)

#undef S3
#undef STEP1
#undef WVAL
#undef WCOMP
    }
  } else {
    constexpr int PER = S / 16;          // 16 / 4 / 1
    #pragma unroll
    for (int u = 0; u < PER; ++u) {
      const int s  = ss * PER + u;
      const int yo = s / Wd, xo = s % Wd;
      const float wx = wsrc[s];
      #pragma unroll
      for (int q = 0; q < 9; ++q) {
        const int ci = q / 3, dy = q % 3;
        const int base = ci * 1156 + (yo * STRIDE + dy + 1) * 34 + (xo * STRIDE + 1);
        #pragma unroll
        for (int dx = 0; dx < 3; ++dx)
          acc[ci * 9 + dy * 3 + dx] = fmaf(wx, s_xi[base + dx], acc[ci * 9 + dy * 3 + dx]);
      }
      acc[27] += wx;
    }
  }

  // reduce across the 16 spatial subs (contiguous 16-lane groups)
  #pragma unroll
  for (int j = 0; j < 28; ++j) {
    float v = acc[j];
    v += __shfl_xor(v, 1, 64);
    v += __shfl_xor(v, 2, 64);
    v += __shfl_xor(v, 4, 64);
    v += __shfl_xor(v, 8, 64);
    acc[j] = v;
  }
  if (ss == 0) {
    #pragma unroll
    for (int j = 0; j < 27; ++j) s_g[(wh * 10 + kk) * 27 + j] = acc[j];
    s_rs[wh * 10 + kk] = acc[27];
  }
  __syncthreads();

  // ---- phase 4: fused std + eps + mahal (no s_std buffer) ----
  float macc[10];
  #pragma unroll
  for (int k2 = 0; k2 < 10; ++k2) macc[k2] = 0.0f;
  for (int c = t; c < C; c += 320) {
    float fw[27];
    #pragma unroll
    for (int j = 0; j < 27; ++j) fw[j] = feat_w[c * 27 + j];
    const float fb = feat_b[c];
    #pragma unroll
    for (int k2 = 0; k2 < 10; ++k2) {
      float a2 = 0.0f;
      #pragma unroll
      for (int j = 0; j < 27; ++j) a2 = fmaf(s_g[(10 + k2) * 27 + j], fw[j], a2);
      a2 = fmaf(fb, s_rs[10 + k2], a2) + A.std_b[I][k2];
      const float eps = jax_normal_pt(fk0, fk1, (uint32_t)((b * 10 + k2) * C + c));
      macc[k2] = fmaf(a2 * a2, eps * eps, macc[k2]);
    }
  }
  const int lane = t & 63, wvi = t >> 6;
  #pragma unroll
  for (int k2 = 0; k2 < 10; ++k2) {
    float v = macc[k2];
    #pragma unroll
    for (int off = 32; off > 0; off >>= 1) v += __shfl_down(v, off, 64);
    if (lane == 0) s_pt[k2 * 5 + wvi] = v;
  }
  __syncthreads();
  if (t == 0) {
    float best = -INFINITY; int bi = 0;
    #pragma unroll
    for (int k2 = 0; k2 < 10; ++k2) {
      float m = -0.5f * (s_pt[k2 * 5 + 0] + s_pt[k2 * 5 + 1] + s_pt[k2 * 5 + 2] +
                         s_pt[k2 * 5 + 3] + s_pt[k2 * 5 + 4]);
      if (m > best) { best = m; bi = k2; }
    }
    A.scores[b * 5 + I] = best;
    *s_idx = bi;
  }
  __syncthreads();

  // ---- phase 5: outputs (mean & std recomputed for the argmax class) ----
  const int idx = *s_idx;
  for (int c = t; c < C; c += 320) {
    float fw[27];
    #pragma unroll
    for (int j = 0; j < 27; ++j) fw[j] = feat_w[c * 27 + j];
    const float fb = feat_b[c];
    float a1 = 0.0f, a2 = 0.0f;
    #pragma unroll
    for (int j = 0; j < 27; ++j) {
      a1 = fmaf(s_g[idx * 27 + j], fw[j], a1);
      a2 = fmaf(s_g[(10 + idx) * 27 + j], fw[j], a2);
    }
    a1 = fmaf(fb, s_rs[idx], a1) + A.mu_b[I][idx];
    a2 = fmaf(fb, s_rs[10 + idx], a2) + A.std_b[I][idx];
    A.mean_out[I][(size_t)b * C + c] = a1;
    A.std_out[I][(size_t)b * C + c]  = a2;
  }
}

__global__ __launch_bounds__(320)
void ood_all(OodArgs A) {
  __shared__ float smem[SMEM_FLOATS];
  switch (blockIdx.x) {
    case 0: stage_body<0,  64, 1024, 1>(A, smem); break;
    case 1: stage_body<1,  64, 1024, 1>(A, smem); break;
    case 2: stage_body<2, 128,  256, 2>(A, smem); break;
    case 3: stage_body<3, 256,   64, 4>(A, smem); break;
    default: stage_body<4, 512,  16, 8>(A, smem); break;
  }
}

__global__ void ood_clf(const float* __restrict__ scores,  // (B,5)
                        const float* __restrict__ clf_w,   // (1,5)
                        const float* __restrict__ clf_b,   // (1,)
                        float* __restrict__ out) {         // (B,)
  int b = blockIdx.x * blockDim.x + threadIdx.x;
  if (b < B_SZ) {
    float acc = clf_b[0];
    #pragma unroll
    for (int i = 0; i < 5; ++i) acc = fmaf(scores[b * 5 + i], clf_w[i], acc);
    out[b] = acc;
  }
}

extern "C" void kernel_launch(void* const* d_in, const int* in_sizes, int n_in,
                              void* d_out, int out_size, void* d_ws, size_t ws_size,
                              hipStream_t stream) {
  (void)in_sizes; (void)n_in; (void)out_size; (void)ws_size;
  const float* clf_w = (const float*)d_in[33];
  const float* clf_b = (const float*)d_in[34];
  float* out    = (float*)d_out;
  float* scores = (float*)d_ws;   // B*5 floats

  OodArgs A;
  A.x       = (const float*)d_in[0];
  A.noise_w = (const float*)d_in[1];
  A.noise_b = (const float*)d_in[2];
  const size_t NMEAN = 1048576;
  const size_t moff[5] = {1024, 66560, 132096, 263168, 525312};
  for (int i = 0; i < 5; ++i) {
    A.feat_w[i]   = (const float*)d_in[3 + 6 * i];
    A.feat_b[i]   = (const float*)d_in[4 + 6 * i];
    A.mu_w[i]     = (const float*)d_in[5 + 6 * i];
    A.mu_b[i]     = (const float*)d_in[6 + 6 * i];
    A.std_w[i]    = (const float*)d_in[7 + 6 * i];
    A.std_b[i]    = (const float*)d_in[8 + 6 * i];
    A.mean_out[i] = out + moff[i];
    A.std_out[i]  = out + moff[i] + NMEAN;
    tf2x32(0u, 42u, 0u, (uint32_t)i, A.fk0[i], A.fk1[i]);
  }
  A.scores = scores;

  ood_all<<<dim3(5, B_SZ), 320, 0, stream>>>(A);
  ood_clf<<<(B_SZ + 255) / 256, 256, 0, stream>>>(scores, clf_w, clf_b, out);
}

// Round 4
// 784.086 us; speedup vs baseline: 2.1083x; 1.0558x over previous
//
#include <hip/hip_runtime.h>
#include <cstdint>

#define B_SZ 1024

// ---------------------------------------------------------------------------
// Threefry-2x32 (20 rounds), exactly as jax._src.prng.threefry2x32.
// ---------------------------------------------------------------------------
__host__ __device__ inline void tf2x32(uint32_t k0, uint32_t k1,
                                       uint32_t x0, uint32_t x1,
                                       uint32_t& o0, uint32_t& o1) {
  uint32_t ks2 = 0x1BD11BDAu ^ k0 ^ k1;
#define TF_RND(r) { x0 += x1; x1 = (x1 << (r)) | (x1 >> (32 - (r))); x1 ^= x0; }
  x0 += k0; x1 += k1;
  TF_RND(13) TF_RND(15) TF_RND(26) TF_RND(6)
  x0 += k1; x1 += ks2 + 1u;
  TF_RND(17) TF_RND(29) TF_RND(16) TF_RND(24)
  x0 += ks2; x1 += k0 + 2u;
  TF_RND(13) TF_RND(15) TF_RND(26) TF_RND(6)
  x0 += k0; x1 += k1 + 3u;
  TF_RND(17) TF_RND(29) TF_RND(16) TF_RND(24)
  x0 += k1; x1 += ks2 + 4u;
  TF_RND(13) TF_RND(15) TF_RND(26) TF_RND(6)
  x0 += ks2; x1 += k0 + 5u;
#undef TF_RND
  o0 = x0; o1 = x1;
}

// XLA ErfInv f32 expansion, identical coefficients.
__device__ inline float erfinv_f32(float x) {
  float w = -log1pf(-x * x);
  float p;
  if (w < 5.0f) {
    w -= 2.5f;
    p = 2.81022636e-08f;
    p = fmaf(p, w, 3.43273939e-07f);
    p = fmaf(p, w, -3.5233877e-06f);
    p = fmaf(p, w, -4.39150654e-06f);
    p = fmaf(p, w, 0.00021858087f);
    p = fmaf(p, w, -0.00125372503f);
    p = fmaf(p, w, -0.00417768164f);
    p = fmaf(p, w, 0.246640727f);
    p = fmaf(p, w, 1.50140941f);
  } else {
    w = sqrtf(w) - 3.0f;
    p = -0.000200214257f;
    p = fmaf(p, w, 0.000100950558f);
    p = fmaf(p, w, 0.00134934322f);
    p = fmaf(p, w, -0.00367342844f);
    p = fmaf(p, w, 0.00573950773f);
    p = fmaf(p, w, -0.0076224613f);
    p = fmaf(p, w, 0.00943887047f);
    p = fmaf(p, w, 1.00167406f);
    p = fmaf(p, w, 2.83297682f);
  }
  return p * x;
}

__device__ inline float jax_normal_pt(uint32_t k0, uint32_t k1, uint32_t e) {
  uint32_t o0, o1;
  tf2x32(k0, k1, 0u, e, o0, o1);
  uint32_t bits = o0 ^ o1;
  float f = __uint_as_float((bits >> 9) | 0x3f800000u) - 1.0f;
  const float LO = -0.99999994f;
  float u = fmaxf(LO, fmaf(f, 2.0f, LO));
  return 1.41421356f * erfinv_f32(u);
}

struct OodArgs {
  const float* x;
  const float* noise_w;
  const float* noise_b;
  const float* feat_w[5];
  const float* feat_b[5];
  const float* mu_w[5];
  const float* mu_b[5];
  const float* std_w[5];
  const float* std_b[5];
  float* mean_out[5];
  float* std_out[5];
  float* scores;
  uint32_t fk0[5], fk1[5];
};

// LDS carve offsets (floats)
#define OFF_X    0      // 3072
#define OFF_XI   3072   // 3*34*34 = 3468
#define OFF_G    6540   // 2*10*27 = 540
#define OFF_RS   7080   // 20
#define OFF_PART 7100   // 50
#define OFF_NW   7150   // 81
#define OFF_NB   7231   // 3
#define OFF_IDX  7235   // 1 (int)
#define SMEM_FLOATS 7236

// ---------------------------------------------------------------------------
// One block per (b, stage I). 320 threads: 20 (wh,k) groups x 16 spatial subs.
// ---------------------------------------------------------------------------
template<int I, int C, int S, int STRIDE>
__device__ __forceinline__ void stage_body(const OodArgs& A_, float* smem) {
  constexpr int Wd = 32 / STRIDE;   // output width

  const int b = blockIdx.x;
  const int t = threadIdx.x;

  float* s_x  = smem + OFF_X;
  float* s_xi = smem + OFF_XI;
  float* s_g  = smem + OFF_G;      // [2][10][27]
  float* s_rs = smem + OFF_RS;     // [2][10]
  float* s_pt = smem + OFF_PART;   // [10][5]
  float* s_nw = smem + OFF_NW;
  float* s_nb = smem + OFF_NB;
  int*   s_idx = (int*)(smem + OFF_IDX);

  const float* feat_w = A_.feat_w[I];
  const float* feat_b = A_.feat_b[I];
  const uint32_t fk0 = A_.fk0[I], fk1 = A_.fk1[I];

  // ---- phase 1: load x[b], zero padded xi, noise weights ----
  const float* xb = A_.x + (size_t)b * 3072;
  for (int p = t; p < 3072; p += 320) s_x[p] = xb[p];
  for (int p = t; p < 3 * 34 * 34; p += 320) s_xi[p] = 0.0f;
  if (t < 81) s_nw[t] = A_.noise_w[81 * I + t];
  if (t < 3)  s_nb[t] = A_.noise_b[3 * I + t];
  __syncthreads();

  // ---- phase 2: xi = x + conv3x3(x, noise_w), into padded layout ----
  for (int p = t; p < 3072; p += 320) {
    int ci = p >> 10; int rr = p & 1023; int yy = rr >> 5; int xx = rr & 31;
    float acc0 = s_nb[ci];
    #pragma unroll
    for (int c2 = 0; c2 < 3; ++c2) {
      #pragma unroll
      for (int dy = 0; dy < 3; ++dy) {
        int y2 = yy + dy - 1;
        if (y2 < 0 || y2 > 31) continue;
        #pragma unroll
        for (int dx = 0; dx < 3; ++dx) {
          int x2 = xx + dx - 1;
          if (x2 < 0 || x2 > 31) continue;
          acc0 = fmaf(s_x[c2 * 1024 + y2 * 32 + x2],
                      s_nw[ci * 27 + c2 * 9 + dy * 3 + dx], acc0);
        }
      }
    }
    s_xi[ci * 1156 + (yy + 1) * 34 + (xx + 1)] = acc0 + s_x[p];
  }
  __syncthreads();

  // ---- phase 3: g[wh][k][j] = sum_s w[k,s]*xi[patch(s,j)], rowsum ----
  const int G  = t >> 4;          // 0..19
  const int ss = t & 15;          // spatial sub
  const int wh = G & 1;
  const int kk = G >> 1;
  const float* wsrc = (wh ? A_.std_w[I] : A_.mu_w[I]) + kk * S;

  float acc[28];
  #pragma unroll
  for (int j = 0; j < 28; ++j) acc[j] = 0.0f;

  if constexpr (STRIDE == 1) {
    // thread ss owns output rows R0=2ss, R1=2ss+1; 4 shared padded row-streams.
    const float* wr0 = wsrc + (2 * ss) * 32;
    const float* wr1 = wr0 + 32;
    #pragma unroll
    for (int ci = 0; ci < 3; ++ci) {
      const int rb = ci * 1156 + (2 * ss) * 34;  // stream u at rb + u*34
      float Av[4], Bv[4], Cv[4];
      float4 w04, w14;
      #pragma unroll
      for (int u = 0; u < 4; ++u) {
        Av[u] = s_xi[rb + u * 34 + 0];
        Bv[u] = s_xi[rb + u * 34 + 1];
      }
#define WCOMP(V, L) ((L) == 0 ? (V).x : (L) == 1 ? (V).y : (L) == 2 ? (V).z : (V).w)
#define LDW(c) { w04 = *(const float4*)(wr0 + (c)); w14 = *(const float4*)(wr1 + (c)); }
#define STEP(c, P, Q, R) { \
    _Pragma("unroll") \
    for (int u = 0; u < 4; ++u) R[u] = s_xi[rb + u * 34 + (c) + 2]; \
    const float w0c = WCOMP(w04, (c) & 3); \
    const float w1c = WCOMP(w14, (c) & 3); \
    _Pragma("unroll") \
    for (int dy = 0; dy < 3; ++dy) { \
      acc[ci*9+dy*3+0] = fmaf(w0c, P[dy], fmaf(w1c, P[dy+1], acc[ci*9+dy*3+0])); \
      acc[ci*9+dy*3+1] = fmaf(w0c, Q[dy], fmaf(w1c, Q[dy+1], acc[ci*9+dy*3+1])); \
      acc[ci*9+dy*3+2] = fmaf(w0c, R[dy], fmaf(w1c, R[dy+1], acc[ci*9+dy*3+2])); \
    } \
    if (ci == 0) acc[27] += w0c + w1c; \
  }
#define G4_0(c) LDW(c) STEP(c, Av, Bv, Cv) STEP((c)+1, Bv, Cv, Av) STEP((c)+2, Cv, Av, Bv) STEP((c)+3, Av, Bv, Cv)
#define G4_1(c) LDW(c) STEP(c, Bv, Cv, Av) STEP((c)+1, Cv, Av, Bv) STEP((c)+2, Av, Bv, Cv) STEP((c)+3, Bv, Cv, Av)
#define G4_2(c) LDW(c) STEP(c, Cv, Av, Bv) STEP((c)+1, Av, Bv, Cv) STEP((c)+2, Bv, Cv, Av) STEP((c)+3, Cv, Av, Bv)

      G4_0(0) G4_1(4) G4_2(8) G4_0(12) G4_1(16) G4_2(20) G4_0(24) G4_1(28)

#undef G4_0
#undef G4_1
#undef G4_2
#undef STEP
#undef LDW
#undef WCOMP
    }
  } else {
    constexpr int PER = S / 16;          // 16 / 4 / 1
    #pragma unroll
    for (int u = 0; u < PER; ++u) {
      const int s  = ss * PER + u;
      const int yo = s / Wd, xo = s % Wd;
      const float wx = wsrc[s];
      #pragma unroll
      for (int q = 0; q < 9; ++q) {
        const int ci = q / 3, dy = q % 3;
        const int base = ci * 1156 + (yo * STRIDE + dy + 1) * 34 + (xo * STRIDE + 1);
        #pragma unroll
        for (int dx = 0; dx < 3; ++dx)
          acc[ci * 9 + dy * 3 + dx] = fmaf(wx, s_xi[base + dx], acc[ci * 9 + dy * 3 + dx]);
      }
      acc[27] += wx;
    }
  }

  // reduce across the 16 spatial subs (contiguous 16-lane groups)
  #pragma unroll
  for (int j = 0; j < 28; ++j) {
    float v = acc[j];
    v += __shfl_xor(v, 1, 64);
    v += __shfl_xor(v, 2, 64);
    v += __shfl_xor(v, 4, 64);
    v += __shfl_xor(v, 8, 64);
    acc[j] = v;
  }
  if (ss == 0) {
    #pragma unroll
    for (int j = 0; j < 27; ++j) s_g[(wh * 10 + kk) * 27 + j] = acc[j];
    s_rs[wh * 10 + kk] = acc[27];
  }
  __syncthreads();

  // ---- phase 4: fused std + eps + mahal (no s_std buffer) ----
  float macc[10];
  #pragma unroll
  for (int k2 = 0; k2 < 10; ++k2) macc[k2] = 0.0f;
  for (int c = t; c < C; c += 320) {
    float fw[27];
    #pragma unroll
    for (int j = 0; j < 27; ++j) fw[j] = feat_w[c * 27 + j];
    const float fb = feat_b[c];
    #pragma unroll
    for (int k2 = 0; k2 < 10; ++k2) {
      float a2 = 0.0f;
      #pragma unroll
      for (int j = 0; j < 27; ++j) a2 = fmaf(s_g[(10 + k2) * 27 + j], fw[j], a2);
      a2 = fmaf(fb, s_rs[10 + k2], a2) + A_.std_b[I][k2];
      const float eps = jax_normal_pt(fk0, fk1, (uint32_t)((b * 10 + k2) * C + c));
      macc[k2] = fmaf(a2 * a2, eps * eps, macc[k2]);
    }
  }
  const int lane = t & 63, wvi = t >> 6;
  #pragma unroll
  for (int k2 = 0; k2 < 10; ++k2) {
    float v = macc[k2];
    #pragma unroll
    for (int off = 32; off > 0; off >>= 1) v += __shfl_down(v, off, 64);
    if (lane == 0) s_pt[k2 * 5 + wvi] = v;
  }
  __syncthreads();
  if (t == 0) {
    float best = -INFINITY; int bi = 0;
    #pragma unroll
    for (int k2 = 0; k2 < 10; ++k2) {
      float m = -0.5f * (s_pt[k2 * 5 + 0] + s_pt[k2 * 5 + 1] + s_pt[k2 * 5 + 2] +
                         s_pt[k2 * 5 + 3] + s_pt[k2 * 5 + 4]);
      if (m > best) { best = m; bi = k2; }
    }
    A_.scores[b * 5 + I] = best;
    *s_idx = bi;
  }
  __syncthreads();

  // ---- phase 5: outputs (mean & std recomputed for the argmax class) ----
  const int idx = *s_idx;
  for (int c = t; c < C; c += 320) {
    float fw[27];
    #pragma unroll
    for (int j = 0; j < 27; ++j) fw[j] = feat_w[c * 27 + j];
    const float fb = feat_b[c];
    float a1 = 0.0f, a2 = 0.0f;
    #pragma unroll
    for (int j = 0; j < 27; ++j) {
      a1 = fmaf(s_g[idx * 27 + j], fw[j], a1);
      a2 = fmaf(s_g[(10 + idx) * 27 + j], fw[j], a2);
    }
    a1 = fmaf(fb, s_rs[idx], a1) + A_.mu_b[I][idx];
    a2 = fmaf(fb, s_rs[10 + idx], a2) + A_.std_b[I][idx];
    A_.mean_out[I][(size_t)b * C + c] = a1;
    A_.std_out[I][(size_t)b * C + c]  = a2;
  }
}

__global__ __launch_bounds__(320)
void ood_all(OodArgs A_) {
  __shared__ float smem[SMEM_FLOATS];
  switch (blockIdx.y) {
    case 0: stage_body<0,  64, 1024, 1>(A_, smem); break;
    case 1: stage_body<1,  64, 1024, 1>(A_, smem); break;
    case 2: stage_body<2, 128,  256, 2>(A_, smem); break;
    case 3: stage_body<3, 256,   64, 4>(A_, smem); break;
    default: stage_body<4, 512,  16, 8>(A_, smem); break;
  }
}

__global__ void ood_clf(const float* __restrict__ scores,  // (B,5)
                        const float* __restrict__ clf_w,   // (1,5)
                        const float* __restrict__ clf_b,   // (1,)
                        float* __restrict__ out) {         // (B,)
  int b = blockIdx.x * blockDim.x + threadIdx.x;
  if (b < B_SZ) {
    float acc = clf_b[0];
    #pragma unroll
    for (int i = 0; i < 5; ++i) acc = fmaf(scores[b * 5 + i], clf_w[i], acc);
    out[b] = acc;
  }
}

extern "C" void kernel_launch(void* const* d_in, const int* in_sizes, int n_in,
                              void* d_out, int out_size, void* d_ws, size_t ws_size,
                              hipStream_t stream) {
  (void)in_sizes; (void)n_in; (void)out_size; (void)ws_size;
  const float* clf_w = (const float*)d_in[33];
  const float* clf_b = (const float*)d_in[34];
  float* out    = (float*)d_out;
  float* scores = (float*)d_ws;   // B*5 floats

  OodArgs A_;
  A_.x       = (const float*)d_in[0];
  A_.noise_w = (const float*)d_in[1];
  A_.noise_b = (const float*)d_in[2];
  const size_t NMEAN = 1048576;
  const size_t moff[5] = {1024, 66560, 132096, 263168, 525312};
  for (int i = 0; i < 5; ++i) {
    A_.feat_w[i]   = (const float*)d_in[3 + 6 * i];
    A_.feat_b[i]   = (const float*)d_in[4 + 6 * i];
    A_.mu_w[i]     = (const float*)d_in[5 + 6 * i];
    A_.mu_b[i]     = (const float*)d_in[6 + 6 * i];
    A_.std_w[i]    = (const float*)d_in[7 + 6 * i];
    A_.std_b[i]    = (const float*)d_in[8 + 6 * i];
    A_.mean_out[i] = out + moff[i];
    A_.std_out[i]  = out + moff[i] + NMEAN;
    tf2x32(0u, 42u, 0u, (uint32_t)i, A_.fk0[i], A_.fk1[i]);
  }
  A_.scores = scores;

  ood_all<<<dim3(B_SZ, 5), 320, 0, stream>>>(A_);
  ood_clf<<<(B_SZ + 255) / 256, 256, 0, stream>>>(scores, clf_w, clf_b, out);
}

// Round 5
// 616.187 us; speedup vs baseline: 2.6828x; 1.2725x over previous
//
#include <hip/hip_runtime.h>
#include <cstdint>

#define B_SZ 1024

// ---------------------------------------------------------------------------
// Threefry-2x32 (20 rounds), exactly as jax._src.prng.threefry2x32.
// ---------------------------------------------------------------------------
__host__ __device__ inline void tf2x32(uint32_t k0, uint32_t k1,
                                       uint32_t x0, uint32_t x1,
                                       uint32_t& o0, uint32_t& o1) {
  uint32_t ks2 = 0x1BD11BDAu ^ k0 ^ k1;
#define TF_RND(r) { x0 += x1; x1 = (x1 << (r)) | (x1 >> (32 - (r))); x1 ^= x0; }
  x0 += k0; x1 += k1;
  TF_RND(13) TF_RND(15) TF_RND(26) TF_RND(6)
  x0 += k1; x1 += ks2 + 1u;
  TF_RND(17) TF_RND(29) TF_RND(16) TF_RND(24)
  x0 += ks2; x1 += k0 + 2u;
  TF_RND(13) TF_RND(15) TF_RND(26) TF_RND(6)
  x0 += k0; x1 += k1 + 3u;
  TF_RND(17) TF_RND(29) TF_RND(16) TF_RND(24)
  x0 += k1; x1 += ks2 + 4u;
  TF_RND(13) TF_RND(15) TF_RND(26) TF_RND(6)
  x0 += ks2; x1 += k0 + 5u;
#undef TF_RND
  o0 = x0; o1 = x1;
}

// XLA ErfInv f32 expansion, identical coefficients.
__device__ inline float erfinv_f32(float x) {
  float w = -log1pf(-x * x);
  float p;
  if (w < 5.0f) {
    w -= 2.5f;
    p = 2.81022636e-08f;
    p = fmaf(p, w, 3.43273939e-07f);
    p = fmaf(p, w, -3.5233877e-06f);
    p = fmaf(p, w, -4.39150654e-06f);
    p = fmaf(p, w, 0.00021858087f);
    p = fmaf(p, w, -0.00125372503f);
    p = fmaf(p, w, -0.00417768164f);
    p = fmaf(p, w, 0.246640727f);
    p = fmaf(p, w, 1.50140941f);
  } else {
    w = sqrtf(w) - 3.0f;
    p = -0.000200214257f;
    p = fmaf(p, w, 0.000100950558f);
    p = fmaf(p, w, 0.00134934322f);
    p = fmaf(p, w, -0.00367342844f);
    p = fmaf(p, w, 0.00573950773f);
    p = fmaf(p, w, -0.0076224613f);
    p = fmaf(p, w, 0.00943887047f);
    p = fmaf(p, w, 1.00167406f);
    p = fmaf(p, w, 2.83297682f);
  }
  return p * x;
}

__device__ inline float jax_normal_pt(uint32_t k0, uint32_t k1, uint32_t e) {
  uint32_t o0, o1;
  tf2x32(k0, k1, 0u, e, o0, o1);
  uint32_t bits = o0 ^ o1;
  float f = __uint_as_float((bits >> 9) | 0x3f800000u) - 1.0f;
  const float LO = -0.99999994f;
  float u = fmaxf(LO, fmaf(f, 2.0f, LO));
  return 1.41421356f * erfinv_f32(u);
}

struct OodArgs {
  const float* x;
  const float* noise_w;
  const float* noise_b;
  const float* feat_w[5];
  const float* feat_b[5];
  const float* mu_w[5];
  const float* mu_b[5];
  const float* std_w[5];
  const float* std_b[5];
  float* mean_out[5];
  float* std_out[5];
  float* scores;
  uint32_t fk0[5], fk1[5];
};

// LDS carve offsets (floats).  s_std (10*C <= 5120 floats) aliases the
// s_x/s_xi region, both dead after phase 3.
#define OFF_X    0      // 3072
#define OFF_XI   3072   // 3*34*34 = 3468
#define OFF_STD  0      // 10*C (max 5120) -- aliases X/XI
#define OFF_G    6540   // 2*10*27 = 540
#define OFF_RS   7080   // 20
#define OFF_PART 7100   // 50
#define OFF_NW   7150   // 81
#define OFF_NB   7231   // 3
#define OFF_IDX  7235   // 1 (int)
#define SMEM_FLOATS 7236

// ---------------------------------------------------------------------------
// One block per (b, stage I). 320 threads: 20 (wh,k) groups x 16 spatial subs.
// ---------------------------------------------------------------------------
template<int I, int C, int S, int STRIDE>
__device__ __forceinline__ void stage_body(const OodArgs& A_, float* smem) {
  constexpr int Wd = 32 / STRIDE;   // output width

  const int b = blockIdx.x;
  const int t = threadIdx.x;

  float* s_x   = smem + OFF_X;
  float* s_xi  = smem + OFF_XI;
  float* s_std = smem + OFF_STD;   // [10][C], aliases s_x/s_xi
  float* s_g   = smem + OFF_G;     // [2][10][27]
  float* s_rs  = smem + OFF_RS;    // [2][10]
  float* s_pt  = smem + OFF_PART;  // [10][5]
  float* s_nw  = smem + OFF_NW;
  float* s_nb  = smem + OFF_NB;
  int*   s_idx = (int*)(smem + OFF_IDX);

  const float* feat_w = A_.feat_w[I];
  const float* feat_b = A_.feat_b[I];
  const uint32_t fk0 = A_.fk0[I], fk1 = A_.fk1[I];

  // ---- phase 1: load x[b], zero padded xi, noise weights ----
  const float* xb = A_.x + (size_t)b * 3072;
  for (int p = t; p < 3072; p += 320) s_x[p] = xb[p];
  for (int p = t; p < 3 * 34 * 34; p += 320) s_xi[p] = 0.0f;
  if (t < 81) s_nw[t] = A_.noise_w[81 * I + t];
  if (t < 3)  s_nb[t] = A_.noise_b[3 * I + t];
  __syncthreads();

  // ---- phase 2: xi = x + conv3x3(x, noise_w), into padded layout ----
  for (int p = t; p < 3072; p += 320) {
    int ci = p >> 10; int rr = p & 1023; int yy = rr >> 5; int xx = rr & 31;
    float acc0 = s_nb[ci];
    #pragma unroll
    for (int c2 = 0; c2 < 3; ++c2) {
      #pragma unroll
      for (int dy = 0; dy < 3; ++dy) {
        int y2 = yy + dy - 1;
        if (y2 < 0 || y2 > 31) continue;
        #pragma unroll
        for (int dx = 0; dx < 3; ++dx) {
          int x2 = xx + dx - 1;
          if (x2 < 0 || x2 > 31) continue;
          acc0 = fmaf(s_x[c2 * 1024 + y2 * 32 + x2],
                      s_nw[ci * 27 + c2 * 9 + dy * 3 + dx], acc0);
        }
      }
    }
    s_xi[ci * 1156 + (yy + 1) * 34 + (xx + 1)] = acc0 + s_x[p];
  }
  __syncthreads();

  // ---- phase 3: g[wh][k][j] = sum_s w[k,s]*xi[patch(s,j)], rowsum ----
  const int G  = t >> 4;          // 0..19
  const int ss = t & 15;          // spatial sub
  const int wh = G & 1;
  const int kk = G >> 1;
  const float* wsrc = (wh ? A_.std_w[I] : A_.mu_w[I]) + kk * S;

  float acc[28];
  #pragma unroll
  for (int j = 0; j < 28; ++j) acc[j] = 0.0f;

  if constexpr (STRIDE == 1) {
    // thread ss owns output rows R0=2ss, R1=2ss+1; 4 shared padded row-streams.
    const float* wr0 = wsrc + (2 * ss) * 32;
    const float* wr1 = wr0 + 32;
    #pragma unroll
    for (int ci = 0; ci < 3; ++ci) {
      const int rb = ci * 1156 + (2 * ss) * 34;  // stream u at rb + u*34
      float Av[4], Bv[4], Cv[4];
      float4 w04, w14;
      #pragma unroll
      for (int u = 0; u < 4; ++u) {
        Av[u] = s_xi[rb + u * 34 + 0];
        Bv[u] = s_xi[rb + u * 34 + 1];
      }
#define WCOMP(V, L) ((L) == 0 ? (V).x : (L) == 1 ? (V).y : (L) == 2 ? (V).z : (V).w)
#define LDW(c) { w04 = *(const float4*)(wr0 + (c)); w14 = *(const float4*)(wr1 + (c)); }
#define STEP(c, P, Q, R) { \
    _Pragma("unroll") \
    for (int u = 0; u < 4; ++u) R[u] = s_xi[rb + u * 34 + (c) + 2]; \
    const float w0c = WCOMP(w04, (c) & 3); \
    const float w1c = WCOMP(w14, (c) & 3); \
    _Pragma("unroll") \
    for (int dy = 0; dy < 3; ++dy) { \
      acc[ci*9+dy*3+0] = fmaf(w0c, P[dy], fmaf(w1c, P[dy+1], acc[ci*9+dy*3+0])); \
      acc[ci*9+dy*3+1] = fmaf(w0c, Q[dy], fmaf(w1c, Q[dy+1], acc[ci*9+dy*3+1])); \
      acc[ci*9+dy*3+2] = fmaf(w0c, R[dy], fmaf(w1c, R[dy+1], acc[ci*9+dy*3+2])); \
    } \
    if (ci == 0) acc[27] += w0c + w1c; \
  }
#define G4_0(c) LDW(c) STEP(c, Av, Bv, Cv) STEP((c)+1, Bv, Cv, Av) STEP((c)+2, Cv, Av, Bv) STEP((c)+3, Av, Bv, Cv)
#define G4_1(c) LDW(c) STEP(c, Bv, Cv, Av) STEP((c)+1, Cv, Av, Bv) STEP((c)+2, Av, Bv, Cv) STEP((c)+3, Bv, Cv, Av)
#define G4_2(c) LDW(c) STEP(c, Cv, Av, Bv) STEP((c)+1, Av, Bv, Cv) STEP((c)+2, Bv, Cv, Av) STEP((c)+3, Cv, Av, Bv)

      G4_0(0) G4_1(4) G4_2(8) G4_0(12) G4_1(16) G4_2(20) G4_0(24) G4_1(28)

#undef G4_0
#undef G4_1
#undef G4_2
#undef STEP
#undef LDW
#undef WCOMP
    }
  } else {
    constexpr int PER = S / 16;          // 16 / 4 / 1
    #pragma unroll
    for (int u = 0; u < PER; ++u) {
      const int s  = ss * PER + u;
      const int yo = s / Wd, xo = s % Wd;
      const float wx = wsrc[s];
      #pragma unroll
      for (int q = 0; q < 9; ++q) {
        const int ci = q / 3, dy = q % 3;
        const int base = ci * 1156 + (yo * STRIDE + dy + 1) * 34 + (xo * STRIDE + 1);
        #pragma unroll
        for (int dx = 0; dx < 3; ++dx)
          acc[ci * 9 + dy * 3 + dx] = fmaf(wx, s_xi[base + dx], acc[ci * 9 + dy * 3 + dx]);
      }
      acc[27] += wx;
    }
  }

  // reduce across the 16 spatial subs (contiguous 16-lane groups)
  #pragma unroll
  for (int j = 0; j < 28; ++j) {
    float v = acc[j];
    v += __shfl_xor(v, 1, 64);
    v += __shfl_xor(v, 2, 64);
    v += __shfl_xor(v, 4, 64);
    v += __shfl_xor(v, 8, 64);
    acc[j] = v;
  }
  if (ss == 0) {
    #pragma unroll
    for (int j = 0; j < 27; ++j) s_g[(wh * 10 + kk) * 27 + j] = acc[j];
    s_rs[wh * 10 + kk] = acc[27];
  }
  __syncthreads();

  // ---- phase 4a: s_std[k*C+c] for all classes (low pressure, round-1 style)
  for (int v = t; v < 10 * C; v += 320) {
    const int k2 = v / C; const int c = v - k2 * C;
    const float* fw = feat_w + c * 27;
    float a2 = 0.0f;
    #pragma unroll
    for (int j = 0; j < 27; ++j) a2 = fmaf(s_g[(10 + k2) * 27 + j], fw[j], a2);
    a2 = fmaf(feat_b[c], s_rs[10 + k2], a2) + A_.std_b[I][k2];
    s_std[v] = a2;
  }
  __syncthreads();

  // ---- phase 4b: mahal[k] = -0.5 * sum_c var*eps^2 with jax-exact eps ----
  float macc[10];
  #pragma unroll
  for (int k2 = 0; k2 < 10; ++k2) macc[k2] = 0.0f;
  for (int c = t; c < C; c += 320) {
    #pragma unroll
    for (int k2 = 0; k2 < 10; ++k2) {
      const float sd  = s_std[k2 * C + c];
      const float eps = jax_normal_pt(fk0, fk1, (uint32_t)((b * 10 + k2) * C + c));
      macc[k2] = fmaf(sd * sd, eps * eps, macc[k2]);
    }
  }
  const int lane = t & 63, wvi = t >> 6;
  #pragma unroll
  for (int k2 = 0; k2 < 10; ++k2) {
    float v = macc[k2];
    #pragma unroll
    for (int off = 32; off > 0; off >>= 1) v += __shfl_down(v, off, 64);
    if (lane == 0) s_pt[k2 * 5 + wvi] = v;
  }
  __syncthreads();
  if (t == 0) {
    float best = -INFINITY; int bi = 0;
    #pragma unroll
    for (int k2 = 0; k2 < 10; ++k2) {
      float m = -0.5f * (s_pt[k2 * 5 + 0] + s_pt[k2 * 5 + 1] + s_pt[k2 * 5 + 2] +
                         s_pt[k2 * 5 + 3] + s_pt[k2 * 5 + 4]);
      if (m > best) { best = m; bi = k2; }
    }
    A_.scores[b * 5 + I] = best;
    *s_idx = bi;
  }
  __syncthreads();

  // ---- phase 5: outputs (mean recomputed for argmax class; std from LDS) --
  const int idx = *s_idx;
  for (int c = t; c < C; c += 320) {
    const float* fw = feat_w + c * 27;
    float a1 = 0.0f;
    #pragma unroll
    for (int j = 0; j < 27; ++j) a1 = fmaf(s_g[idx * 27 + j], fw[j], a1);
    a1 = fmaf(feat_b[c], s_rs[idx], a1) + A_.mu_b[I][idx];
    A_.mean_out[I][(size_t)b * C + c] = a1;
    A_.std_out[I][(size_t)b * C + c]  = s_std[idx * C + c];
  }
}

__global__ __launch_bounds__(320)
void ood_all(OodArgs A_) {
  __shared__ float smem[SMEM_FLOATS];
  switch (blockIdx.y) {
    case 0: stage_body<0,  64, 1024, 1>(A_, smem); break;
    case 1: stage_body<1,  64, 1024, 1>(A_, smem); break;
    case 2: stage_body<2, 128,  256, 2>(A_, smem); break;
    case 3: stage_body<3, 256,   64, 4>(A_, smem); break;
    default: stage_body<4, 512,  16, 8>(A_, smem); break;
  }
}

__global__ void ood_clf(const float* __restrict__ scores,  // (B,5)
                        const float* __restrict__ clf_w,   // (1,5)
                        const float* __restrict__ clf_b,   // (1,)
                        float* __restrict__ out) {         // (B,)
  int b = blockIdx.x * blockDim.x + threadIdx.x;
  if (b < B_SZ) {
    float acc = clf_b[0];
    #pragma unroll
    for (int i = 0; i < 5; ++i) acc = fmaf(scores[b * 5 + i], clf_w[i], acc);
    out[b] = acc;
  }
}

extern "C" void kernel_launch(void* const* d_in, const int* in_sizes, int n_in,
                              void* d_out, int out_size, void* d_ws, size_t ws_size,
                              hipStream_t stream) {
  (void)in_sizes; (void)n_in; (void)out_size; (void)ws_size;
  const float* clf_w = (const float*)d_in[33];
  const float* clf_b = (const float*)d_in[34];
  float* out    = (float*)d_out;
  float* scores = (float*)d_ws;   // B*5 floats

  OodArgs A_;
  A_.x       = (const float*)d_in[0];
  A_.noise_w = (const float*)d_in[1];
  A_.noise_b = (const float*)d_in[2];
  const size_t NMEAN = 1048576;
  const size_t moff[5] = {1024, 66560, 132096, 263168, 525312};
  for (int i = 0; i < 5; ++i) {
    A_.feat_w[i]   = (const float*)d_in[3 + 6 * i];
    A_.feat_b[i]   = (const float*)d_in[4 + 6 * i];
    A_.mu_w[i]     = (const float*)d_in[5 + 6 * i];
    A_.mu_b[i]     = (const float*)d_in[6 + 6 * i];
    A_.std_w[i]    = (const float*)d_in[7 + 6 * i];
    A_.std_b[i]    = (const float*)d_in[8 + 6 * i];
    A_.mean_out[i] = out + moff[i];
    A_.std_out[i]  = out + moff[i] + NMEAN;
    tf2x32(0u, 42u, 0u, (uint32_t)i, A_.fk0[i], A_.fk1[i]);
  }
  A_.scores = scores;

  ood_all<<<dim3(B_SZ, 5), 320, 0, stream>>>(A_);
  ood_clf<<<(B_SZ + 255) / 256, 256, 0, stream>>>(scores, clf_w, clf_b, out);
}

// Round 6
// 524.060 us; speedup vs baseline: 3.1545x; 1.1758x over previous
//
#include <hip/hip_runtime.h>
#include <cstdint>

#define B_SZ 1024

// ---------------------------------------------------------------------------
// Threefry-2x32 (20 rounds), exactly as jax._src.prng.threefry2x32.
// ---------------------------------------------------------------------------
__host__ __device__ inline void tf2x32(uint32_t k0, uint32_t k1,
                                       uint32_t x0, uint32_t x1,
                                       uint32_t& o0, uint32_t& o1) {
  uint32_t ks2 = 0x1BD11BDAu ^ k0 ^ k1;
#define TF_RND(r) { x0 += x1; x1 = (x1 << (r)) | (x1 >> (32 - (r))); x1 ^= x0; }
  x0 += k0; x1 += k1;
  TF_RND(13) TF_RND(15) TF_RND(26) TF_RND(6)
  x0 += k1; x1 += ks2 + 1u;
  TF_RND(17) TF_RND(29) TF_RND(16) TF_RND(24)
  x0 += ks2; x1 += k0 + 2u;
  TF_RND(13) TF_RND(15) TF_RND(26) TF_RND(6)
  x0 += k0; x1 += k1 + 3u;
  TF_RND(17) TF_RND(29) TF_RND(16) TF_RND(24)
  x0 += k1; x1 += ks2 + 4u;
  TF_RND(13) TF_RND(15) TF_RND(26) TF_RND(6)
  x0 += ks2; x1 += k0 + 5u;
#undef TF_RND
  o0 = x0; o1 = x1;
}

// XLA ErfInv f32 expansion, identical coefficients.
__device__ inline float erfinv_f32(float x) {
  float w = -log1pf(-x * x);
  float p;
  if (w < 5.0f) {
    w -= 2.5f;
    p = 2.81022636e-08f;
    p = fmaf(p, w, 3.43273939e-07f);
    p = fmaf(p, w, -3.5233877e-06f);
    p = fmaf(p, w, -4.39150654e-06f);
    p = fmaf(p, w, 0.00021858087f);
    p = fmaf(p, w, -0.00125372503f);
    p = fmaf(p, w, -0.00417768164f);
    p = fmaf(p, w, 0.246640727f);
    p = fmaf(p, w, 1.50140941f);
  } else {
    w = sqrtf(w) - 3.0f;
    p = -0.000200214257f;
    p = fmaf(p, w, 0.000100950558f);
    p = fmaf(p, w, 0.00134934322f);
    p = fmaf(p, w, -0.00367342844f);
    p = fmaf(p, w, 0.00573950773f);
    p = fmaf(p, w, -0.0076224613f);
    p = fmaf(p, w, 0.00943887047f);
    p = fmaf(p, w, 1.00167406f);
    p = fmaf(p, w, 2.83297682f);
  }
  return p * x;
}

__device__ inline float jax_normal_pt(uint32_t k0, uint32_t k1, uint32_t e) {
  uint32_t o0, o1;
  tf2x32(k0, k1, 0u, e, o0, o1);
  uint32_t bits = o0 ^ o1;
  float f = __uint_as_float((bits >> 9) | 0x3f800000u) - 1.0f;
  const float LO = -0.99999994f;
  float u = fmaxf(LO, fmaf(f, 2.0f, LO));
  return 1.41421356f * erfinv_f32(u);
}

struct OodArgs {
  const float* x;
  const float* noise_w;
  const float* noise_b;
  const float* feat_w[5];
  const float* feat_b[5];
  const float* mu_w[5];
  const float* mu_b[5];
  const float* std_w[5];
  const float* std_b[5];
  float* mean_out[5];
  float* std_out[5];
  float* scores;
  uint32_t fk0[5], fk1[5];
};

// LDS carve offsets (floats).  s_std (10*C <= 5120 floats) aliases the
// s_xp/s_xi region (dead after phase 3).
#define OFF_XP   0      // 3*34*34 = 3468 (padded x)
#define OFF_XI   3468   // 3*34*34 = 3468 (padded noised slice)
#define OFF_STD  0      // 10*C (max 5120) -- aliases XP/XI
#define OFF_G    6936   // 2*10*27 = 540
#define OFF_RS   7476   // 20
#define OFF_PART 7496   // 50
#define OFF_NW   7546   // 81
#define OFF_NB   7627   // 3
#define OFF_IDX  7630   // 1 (int)
#define SMEM_FLOATS 7631

// ---------------------------------------------------------------------------
// One block per (b, stage I). 320 threads: 20 (wh,k) groups x 16 spatial subs.
// ---------------------------------------------------------------------------
template<int I, int C, int S, int STRIDE>
__device__ __forceinline__ void stage_body(const OodArgs& A_, float* smem) {
  constexpr int Wd = 32 / STRIDE;   // output width

  const int b = blockIdx.x;
  const int t = threadIdx.x;

  float* s_xp  = smem + OFF_XP;
  float* s_xi  = smem + OFF_XI;
  float* s_std = smem + OFF_STD;   // [10][C], aliases s_xp/s_xi
  float* s_g   = smem + OFF_G;     // [2][10][27]
  float* s_rs  = smem + OFF_RS;    // [2][10]
  float* s_pt  = smem + OFF_PART;  // [10][5]
  float* s_nw  = smem + OFF_NW;
  float* s_nb  = smem + OFF_NB;
  int*   s_idx = (int*)(smem + OFF_IDX);

  const float* feat_w = A_.feat_w[I];
  const float* feat_b = A_.feat_b[I];
  const uint32_t fk0 = A_.fk0[I], fk1 = A_.fk1[I];

  // ---- phase 1: zero both padded buffers, load x[b] interior, weights ----
  for (int p = t; p < 2 * 3468; p += 320) smem[p] = 0.0f;
  if (t < 81) s_nw[t] = A_.noise_w[81 * I + t];
  if (t < 3)  s_nb[t] = A_.noise_b[3 * I + t];
  __syncthreads();
  const float* xb = A_.x + (size_t)b * 3072;
  for (int p = t; p < 3072; p += 320) {
    int ci = p >> 10; int rr = p & 1023; int yy = rr >> 5; int xx = rr & 31;
    s_xp[ci * 1156 + (yy + 1) * 34 + (xx + 1)] = xb[p];
  }
  __syncthreads();

  // ---- phase 2: xi = x + conv3x3(x, noise_w); branch-free via padding ----
  #pragma unroll
  for (int co = 0; co < 3; ++co) {           // output channel
    float nwr[27];
    #pragma unroll
    for (int j = 0; j < 27; ++j) nwr[j] = s_nw[co * 27 + j];  // broadcast
    const float nb = s_nb[co];
    for (int p = t; p < 1024; p += 320) {
      const int base = (p >> 5) * 34 + (p & 31);   // top-left in padded coords
      float a = nb;
      #pragma unroll
      for (int c2 = 0; c2 < 3; ++c2) {
        #pragma unroll
        for (int q = 0; q < 9; ++q)
          a = fmaf(s_xp[c2 * 1156 + base + (q / 3) * 34 + (q % 3)],
                   nwr[c2 * 9 + q], a);
      }
      s_xi[co * 1156 + base + 35] = a + s_xp[co * 1156 + base + 35];
    }
  }
  __syncthreads();

  // ---- phase 3: g[wh][k][j] = sum_s w[k,s]*xi[patch(s,j)], rowsum ----
  const int G  = t >> 4;          // 0..19
  const int ss = t & 15;          // spatial sub
  const int wh = G & 1;
  const int kk = G >> 1;
  const float* wsrc = (wh ? A_.std_w[I] : A_.mu_w[I]) + kk * S;

  float acc[28];
  #pragma unroll
  for (int j = 0; j < 28; ++j) acc[j] = 0.0f;

  if constexpr (STRIDE == 1) {
    // thread ss owns output rows 2ss, 2ss+1; ci INNER so w loads once.
    const float* wr0 = wsrc + (2 * ss) * 32;
    const float* wr1 = wr0 + 32;
    const int rbase = (2 * ss) * 34;
    float Av[3][4], Bv[3][4], Cv[3][4];
    float4 w04, w14;
    #pragma unroll
    for (int ci = 0; ci < 3; ++ci)
      #pragma unroll
      for (int u = 0; u < 4; ++u) {
        Av[ci][u] = s_xi[ci * 1156 + rbase + u * 34 + 0];
        Bv[ci][u] = s_xi[ci * 1156 + rbase + u * 34 + 1];
      }
#define WCOMP(V, L) ((L) == 0 ? (V).x : (L) == 1 ? (V).y : (L) == 2 ? (V).z : (V).w)
#define LDW(c) { w04 = *(const float4*)(wr0 + (c)); w14 = *(const float4*)(wr1 + (c)); }
#define STEP(c, P, Q, R) { \
    _Pragma("unroll") \
    for (int ci = 0; ci < 3; ++ci) { \
      _Pragma("unroll") \
      for (int u = 0; u < 4; ++u) \
        R[ci][u] = s_xi[ci * 1156 + rbase + u * 34 + (c) + 2]; \
    } \
    const float w0c = WCOMP(w04, (c) & 3); \
    const float w1c = WCOMP(w14, (c) & 3); \
    _Pragma("unroll") \
    for (int ci = 0; ci < 3; ++ci) { \
      _Pragma("unroll") \
      for (int dy = 0; dy < 3; ++dy) { \
        acc[ci*9+dy*3+0] = fmaf(w0c, P[ci][dy], fmaf(w1c, P[ci][dy+1], acc[ci*9+dy*3+0])); \
        acc[ci*9+dy*3+1] = fmaf(w0c, Q[ci][dy], fmaf(w1c, Q[ci][dy+1], acc[ci*9+dy*3+1])); \
        acc[ci*9+dy*3+2] = fmaf(w0c, R[ci][dy], fmaf(w1c, R[ci][dy+1], acc[ci*9+dy*3+2])); \
      } \
    } \
    acc[27] += w0c + w1c; \
  }
#define G4_0(c) LDW(c) STEP(c, Av, Bv, Cv) STEP((c)+1, Bv, Cv, Av) STEP((c)+2, Cv, Av, Bv) STEP((c)+3, Av, Bv, Cv)
#define G4_1(c) LDW(c) STEP(c, Bv, Cv, Av) STEP((c)+1, Cv, Av, Bv) STEP((c)+2, Av, Bv, Cv) STEP((c)+3, Bv, Cv, Av)
#define G4_2(c) LDW(c) STEP(c, Cv, Av, Bv) STEP((c)+1, Av, Bv, Cv) STEP((c)+2, Bv, Cv, Av) STEP((c)+3, Cv, Av, Bv)

    G4_0(0) G4_1(4) G4_2(8) G4_0(12) G4_1(16) G4_2(20) G4_0(24) G4_1(28)

#undef G4_0
#undef G4_1
#undef G4_2
#undef STEP
#undef LDW
#undef WCOMP
  } else {
    constexpr int PER = S / 16;          // 16 / 4 / 1
    #pragma unroll
    for (int u = 0; u < PER; ++u) {
      const int s  = ss * PER + u;
      const int yo = s / Wd, xo = s % Wd;
      const float wx = wsrc[s];
      #pragma unroll
      for (int q = 0; q < 9; ++q) {
        const int ci = q / 3, dy = q % 3;
        const int base = ci * 1156 + (yo * STRIDE + dy + 1) * 34 + (xo * STRIDE + 1);
        #pragma unroll
        for (int dx = 0; dx < 3; ++dx)
          acc[ci * 9 + dy * 3 + dx] = fmaf(wx, s_xi[base + dx], acc[ci * 9 + dy * 3 + dx]);
      }
      acc[27] += wx;
    }
  }

  // reduce across the 16 spatial subs (contiguous 16-lane groups)
  #pragma unroll
  for (int j = 0; j < 28; ++j) {
    float v = acc[j];
    v += __shfl_xor(v, 1, 64);
    v += __shfl_xor(v, 2, 64);
    v += __shfl_xor(v, 4, 64);
    v += __shfl_xor(v, 8, 64);
    acc[j] = v;
  }
  if (ss == 0) {
    #pragma unroll
    for (int j = 0; j < 27; ++j) s_g[(wh * 10 + kk) * 27 + j] = acc[j];
    s_rs[wh * 10 + kk] = acc[27];
  }
  __syncthreads();

  // ---- phase 4a: s_std[k*C+c] for all classes (low pressure) ----
  for (int v = t; v < 10 * C; v += 320) {
    const int k2 = v / C; const int c = v - k2 * C;
    const float* fw = feat_w + c * 27;
    float a2 = 0.0f;
    #pragma unroll
    for (int j = 0; j < 27; ++j) a2 = fmaf(s_g[(10 + k2) * 27 + j], fw[j], a2);
    a2 = fmaf(feat_b[c], s_rs[10 + k2], a2) + A_.std_b[I][k2];
    s_std[v] = a2;
  }
  __syncthreads();

  // ---- phase 4b: mahal[k] = -0.5 * sum_c var*eps^2 with jax-exact eps ----
  float macc[10];
  #pragma unroll
  for (int k2 = 0; k2 < 10; ++k2) macc[k2] = 0.0f;
  for (int c = t; c < C; c += 320) {
    #pragma unroll
    for (int k2 = 0; k2 < 10; ++k2) {
      const float sd  = s_std[k2 * C + c];
      const float eps = jax_normal_pt(fk0, fk1, (uint32_t)((b * 10 + k2) * C + c));
      macc[k2] = fmaf(sd * sd, eps * eps, macc[k2]);
    }
  }
  const int lane = t & 63, wvi = t >> 6;
  #pragma unroll
  for (int k2 = 0; k2 < 10; ++k2) {
    float v = macc[k2];
    #pragma unroll
    for (int off = 32; off > 0; off >>= 1) v += __shfl_down(v, off, 64);
    if (lane == 0) s_pt[k2 * 5 + wvi] = v;
  }
  __syncthreads();
  if (t == 0) {
    float best = -INFINITY; int bi = 0;
    #pragma unroll
    for (int k2 = 0; k2 < 10; ++k2) {
      float m = -0.5f * (s_pt[k2 * 5 + 0] + s_pt[k2 * 5 + 1] + s_pt[k2 * 5 + 2] +
                         s_pt[k2 * 5 + 3] + s_pt[k2 * 5 + 4]);
      if (m > best) { best = m; bi = k2; }
    }
    A_.scores[b * 5 + I] = best;
    *s_idx = bi;
  }
  __syncthreads();

  // ---- phase 5: outputs (mean recomputed for argmax class; std from LDS) --
  const int idx = *s_idx;
  for (int c = t; c < C; c += 320) {
    const float* fw = feat_w + c * 27;
    float a1 = 0.0f;
    #pragma unroll
    for (int j = 0; j < 27; ++j) a1 = fmaf(s_g[idx * 27 + j], fw[j], a1);
    a1 = fmaf(feat_b[c], s_rs[idx], a1) + A_.mu_b[I][idx];
    A_.mean_out[I][(size_t)b * C + c] = a1;
    A_.std_out[I][(size_t)b * C + c]  = s_std[idx * C + c];
  }
}

__global__ __launch_bounds__(320, 5)
void ood_all(OodArgs A_) {
  __shared__ float smem[SMEM_FLOATS];
  switch (blockIdx.y) {
    case 0: stage_body<0,  64, 1024, 1>(A_, smem); break;
    case 1: stage_body<1,  64, 1024, 1>(A_, smem); break;
    case 2: stage_body<2, 128,  256, 2>(A_, smem); break;
    case 3: stage_body<3, 256,   64, 4>(A_, smem); break;
    default: stage_body<4, 512,  16, 8>(A_, smem); break;
  }
}

__global__ void ood_clf(const float* __restrict__ scores,  // (B,5)
                        const float* __restrict__ clf_w,   // (1,5)
                        const float* __restrict__ clf_b,   // (1,)
                        float* __restrict__ out) {         // (B,)
  int b = blockIdx.x * blockDim.x + threadIdx.x;
  if (b < B_SZ) {
    float acc = clf_b[0];
    #pragma unroll
    for (int i = 0; i < 5; ++i) acc = fmaf(scores[b * 5 + i], clf_w[i], acc);
    out[b] = acc;
  }
}

extern "C" void kernel_launch(void* const* d_in, const int* in_sizes, int n_in,
                              void* d_out, int out_size, void* d_ws, size_t ws_size,
                              hipStream_t stream) {
  (void)in_sizes; (void)n_in; (void)out_size; (void)ws_size;
  const float* clf_w = (const float*)d_in[33];
  const float* clf_b = (const float*)d_in[34];
  float* out    = (float*)d_out;
  float* scores = (float*)d_ws;   // B*5 floats

  OodArgs A_;
  A_.x       = (const float*)d_in[0];
  A_.noise_w = (const float*)d_in[1];
  A_.noise_b = (const float*)d_in[2];
  const size_t NMEAN = 1048576;
  const size_t moff[5] = {1024, 66560, 132096, 263168, 525312};
  for (int i = 0; i < 5; ++i) {
    A_.feat_w[i]   = (const float*)d_in[3 + 6 * i];
    A_.feat_b[i]   = (const float*)d_in[4 + 6 * i];
    A_.mu_w[i]     = (const float*)d_in[5 + 6 * i];
    A_.mu_b[i]     = (const float*)d_in[6 + 6 * i];
    A_.std_w[i]    = (const float*)d_in[7 + 6 * i];
    A_.std_b[i]    = (const float*)d_in[8 + 6 * i];
    A_.mean_out[i] = out + moff[i];
    A_.std_out[i]  = out + moff[i] + NMEAN;
    tf2x32(0u, 42u, 0u, (uint32_t)i, A_.fk0[i], A_.fk1[i]);
  }
  A_.scores = scores;

  ood_all<<<dim3(B_SZ, 5), 320, 0, stream>>>(A_);
  ood_clf<<<(B_SZ + 255) / 256, 256, 0, stream>>>(scores, clf_w, clf_b, out);
}